// Round 1
// baseline (3147.719 us; speedup 1.0000x reference)
//
#include <hip/hip_runtime.h>
#include <cstddef>

// Problem constants (reference: B=32, NDOC=4, L=512, E=512)
#define BATCH 32
#define NDOC  4
#define NB    128      // 4*B batched attention rows
#define LL    512
#define EE    512
#define TWO_E 1024
#define SCALE 0.044194173824159216f   // 1/sqrt(512), rounds to np.float32 value
#define NEG_INF -1e9f

// ---------------------------------------------------------------------------
// K1: scores[i,q,k] = mask ? scale * dot(x1[i%32,q,:], x2f[i,k,:]) : -1e9
// Tiled NT GEMM, 64x64 tile, 4x4 register blocking. Writes attn region.
// ---------------------------------------------------------------------------
__global__ __launch_bounds__(256) void k_scores(
    const float* __restrict__ x1, const float* __restrict__ x2,
    const int* __restrict__ x1_len, const int* __restrict__ x2_len,
    float* __restrict__ attn)
{
    __shared__ float At[64][65];   // pad 65: <=2-way LDS aliasing everywhere
    __shared__ float Bt[64][65];
    const int i  = blockIdx.z;
    const int q0 = blockIdx.y * 64;
    const int k0 = blockIdx.x * 64;
    const float* A  = x1 + (size_t)(i & 31) * LL * EE;
    const float* Bm = x2 + (size_t)i * LL * EE;
    const int t  = threadIdx.x;
    const int tx = t & 15, ty = t >> 4;
    const int tx4 = tx * 4, ty4 = ty * 4;
    float acc[4][4] = {};
    for (int e0 = 0; e0 < EE; e0 += 64) {
#pragma unroll
        for (int p = 0; p < 4; ++p) {
            int idx = p * 256 + t;
            int row = idx >> 4;
            int c4  = (idx & 15) * 4;
            float4 av = *(const float4*)(A  + (size_t)(q0 + row) * EE + e0 + c4);
            float4 bv = *(const float4*)(Bm + (size_t)(k0 + row) * EE + e0 + c4);
            At[row][c4] = av.x; At[row][c4+1] = av.y; At[row][c4+2] = av.z; At[row][c4+3] = av.w;
            Bt[row][c4] = bv.x; Bt[row][c4+1] = bv.y; Bt[row][c4+2] = bv.z; Bt[row][c4+3] = bv.w;
        }
        __syncthreads();
#pragma unroll 4
        for (int kk = 0; kk < 64; ++kk) {
            float a[4], b[4];
#pragma unroll
            for (int r = 0; r < 4; ++r) a[r] = At[ty4 + r][kk];
#pragma unroll
            for (int c = 0; c < 4; ++c) b[c] = Bt[tx4 + c][kk];
#pragma unroll
            for (int r = 0; r < 4; ++r)
#pragma unroll
                for (int c = 0; c < 4; ++c)
                    acc[r][c] = fmaf(a[r], b[c], acc[r][c]);
        }
        __syncthreads();
    }
    const int qlen = x1_len[i & 31];
    const int klen = x2_len[i];
    float* op = attn + (size_t)i * LL * LL;
#pragma unroll
    for (int r = 0; r < 4; ++r) {
        int q = q0 + ty4 + r;
#pragma unroll
        for (int c = 0; c < 4; ++c) {
            int k = k0 + tx4 + c;
            float v = (q < qlen && k < klen) ? acc[r][c] * SCALE : NEG_INF;
            op[(size_t)q * LL + k] = v;
        }
    }
}

// ---------------------------------------------------------------------------
// K2: in-place row softmax over 512 cols. One wave per row, 8 elems/lane.
// All-masked rows (-1e9 everywhere) -> uniform 1/512, matching jax.
// ---------------------------------------------------------------------------
__global__ __launch_bounds__(256) void k_softmax(float* __restrict__ attn)
{
    const int row  = blockIdx.x * 4 + (threadIdx.x >> 6);
    const int lane = threadIdx.x & 63;
    float* p = attn + (size_t)row * LL + lane * 8;
    float4 v0 = *(float4*)p;
    float4 v1 = *(float4*)(p + 4);
    float m = fmaxf(fmaxf(fmaxf(v0.x, v0.y), fmaxf(v0.z, v0.w)),
                    fmaxf(fmaxf(v1.x, v1.y), fmaxf(v1.z, v1.w)));
#pragma unroll
    for (int o = 32; o > 0; o >>= 1) m = fmaxf(m, __shfl_xor(m, o));
    v0.x = __expf(v0.x - m); v0.y = __expf(v0.y - m);
    v0.z = __expf(v0.z - m); v0.w = __expf(v0.w - m);
    v1.x = __expf(v1.x - m); v1.y = __expf(v1.y - m);
    v1.z = __expf(v1.z - m); v1.w = __expf(v1.w - m);
    float s = v0.x + v0.y + v0.z + v0.w + v1.x + v1.y + v1.z + v1.w;
#pragma unroll
    for (int o = 32; o > 0; o >>= 1) s += __shfl_xor(s, o);
    const float inv = 1.0f / s;
    v0.x *= inv; v0.y *= inv; v0.z *= inv; v0.w *= inv;
    v1.x *= inv; v1.y *= inv; v1.z *= inv; v1.w *= inv;
    *(float4*)p = v0;
    *(float4*)(p + 4) = v1;
}

// ---------------------------------------------------------------------------
// K3: x1_att[i] = attn[i] @ x2f[i]   (NN GEMM, 512x512x512 per i) -> ws
// ---------------------------------------------------------------------------
__global__ __launch_bounds__(256) void k_pv(
    const float* __restrict__ attn, const float* __restrict__ x2,
    float* __restrict__ xatt)
{
    __shared__ float At[64][65];   // [q][k]
    __shared__ float Bt[64][65];   // [k][e]
    const int i  = blockIdx.z;
    const int q0 = blockIdx.y * 64;
    const int e0 = blockIdx.x * 64;
    const float* A  = attn + (size_t)i * LL * LL;
    const float* Bm = x2   + (size_t)i * LL * EE;
    const int t  = threadIdx.x;
    const int tx = t & 15, ty = t >> 4;
    const int tx4 = tx * 4, ty4 = ty * 4;
    float acc[4][4] = {};
    for (int k0 = 0; k0 < LL; k0 += 64) {
#pragma unroll
        for (int p = 0; p < 4; ++p) {
            int idx = p * 256 + t;
            int row = idx >> 4;
            int c4  = (idx & 15) * 4;
            float4 av = *(const float4*)(A  + (size_t)(q0 + row) * LL + k0 + c4);
            float4 bv = *(const float4*)(Bm + (size_t)(k0 + row) * EE + e0 + c4);
            At[row][c4] = av.x; At[row][c4+1] = av.y; At[row][c4+2] = av.z; At[row][c4+3] = av.w;
            Bt[row][c4] = bv.x; Bt[row][c4+1] = bv.y; Bt[row][c4+2] = bv.z; Bt[row][c4+3] = bv.w;
        }
        __syncthreads();
#pragma unroll 4
        for (int kk = 0; kk < 64; ++kk) {
            float a[4], b[4];
#pragma unroll
            for (int r = 0; r < 4; ++r) a[r] = At[ty4 + r][kk];
#pragma unroll
            for (int c = 0; c < 4; ++c) b[c] = Bt[kk][tx4 + c];
#pragma unroll
            for (int r = 0; r < 4; ++r)
#pragma unroll
                for (int c = 0; c < 4; ++c)
                    acc[r][c] = fmaf(a[r], b[c], acc[r][c]);
        }
        __syncthreads();
    }
    float* op = xatt + (size_t)i * LL * EE;
#pragma unroll
    for (int r = 0; r < 4; ++r)
#pragma unroll
        for (int c = 0; c < 4; ++c)
            op[(size_t)(q0 + ty4 + r) * EE + e0 + tx4 + c] = acc[r][c];
}

// ---------------------------------------------------------------------------
// K4: fus = relu(cat(x1-att, x1*att) @ fusion_w + b), fused mean/max pool
// over L. One block per (i, 64-wide e-tile); loops 8 l-tiles of 64 rows.
// ---------------------------------------------------------------------------
__global__ __launch_bounds__(256) void k_fuse(
    const float* __restrict__ x1, const float* __restrict__ xatt,
    const float* __restrict__ fw, const float* __restrict__ fb,
    float* __restrict__ meanbuf, float* __restrict__ maxbuf)
{
    __shared__ float Ct[64][65];   // [l][j]
    __shared__ float Wt[64][65];   // [j][e]
    __shared__ float red[16][65];
    const int i  = blockIdx.y;
    const int e0 = blockIdx.x * 64;
    const float* xr = x1   + (size_t)(i & 31) * LL * EE;
    const float* xa = xatt + (size_t)i * LL * EE;
    const int t  = threadIdx.x;
    const int tx = t & 15, ty = t >> 4;
    const int tx4 = tx * 4, ty4 = ty * 4;
    float bias[4];
#pragma unroll
    for (int c = 0; c < 4; ++c) bias[c] = fb[e0 + tx4 + c];
    float csum[4] = {0.f, 0.f, 0.f, 0.f};
    float cmax[4] = {-3e38f, -3e38f, -3e38f, -3e38f};

    for (int l0 = 0; l0 < LL; l0 += 64) {
        float acc[4][4] = {};
        for (int j0 = 0; j0 < TWO_E; j0 += 64) {
#pragma unroll
            for (int p = 0; p < 4; ++p) {
                int idx = p * 256 + t;
                int row = idx >> 4;
                int c4  = (idx & 15) * 4;
                int jj  = (j0 < EE) ? (j0 + c4) : (j0 - EE + c4);
                float4 xv = *(const float4*)(xr + (size_t)(l0 + row) * EE + jj);
                float4 av = *(const float4*)(xa + (size_t)(l0 + row) * EE + jj);
                float4 cv;
                if (j0 < EE) { cv.x = xv.x - av.x; cv.y = xv.y - av.y; cv.z = xv.z - av.z; cv.w = xv.w - av.w; }
                else         { cv.x = xv.x * av.x; cv.y = xv.y * av.y; cv.z = xv.z * av.z; cv.w = xv.w * av.w; }
                Ct[row][c4] = cv.x; Ct[row][c4+1] = cv.y; Ct[row][c4+2] = cv.z; Ct[row][c4+3] = cv.w;
                float4 wv = *(const float4*)(fw + (size_t)(j0 + row) * EE + e0 + c4);
                Wt[row][c4] = wv.x; Wt[row][c4+1] = wv.y; Wt[row][c4+2] = wv.z; Wt[row][c4+3] = wv.w;
            }
            __syncthreads();
#pragma unroll 4
            for (int kk = 0; kk < 64; ++kk) {
                float a[4], b[4];
#pragma unroll
                for (int r = 0; r < 4; ++r) a[r] = Ct[ty4 + r][kk];
#pragma unroll
                for (int c = 0; c < 4; ++c) b[c] = Wt[kk][tx4 + c];
#pragma unroll
                for (int r = 0; r < 4; ++r)
#pragma unroll
                    for (int c = 0; c < 4; ++c)
                        acc[r][c] = fmaf(a[r], b[c], acc[r][c]);
            }
            __syncthreads();
        }
#pragma unroll
        for (int r = 0; r < 4; ++r)
#pragma unroll
            for (int c = 0; c < 4; ++c) {
                float f = fmaxf(acc[r][c] + bias[c], 0.f);
                csum[c] += f;
                cmax[c] = fmaxf(cmax[c], f);
            }
    }
    // reduce the 16 thread-rows per column
#pragma unroll
    for (int c = 0; c < 4; ++c) red[ty][tx4 + c] = csum[c];
    __syncthreads();
    if (t < 64) {
        float s = 0.f;
#pragma unroll
        for (int r = 0; r < 16; ++r) s += red[r][t];
        meanbuf[(size_t)i * EE + e0 + t] = s * (1.0f / 512.0f);
    }
    __syncthreads();
#pragma unroll
    for (int c = 0; c < 4; ++c) red[ty][tx4 + c] = cmax[c];
    __syncthreads();
    if (t < 64) {
        float m = -3e38f;
#pragma unroll
        for (int r = 0; r < 16; ++r) m = fmaxf(m, red[r][t]);
        maxbuf[(size_t)i * EE + e0 + t] = m;
    }
}

// ---------------------------------------------------------------------------
// K5: out = relu(pooled @ out_w + out_b).  pooled[b,j] from mean/max bufs via
// the reshape(B,-1) indexing: i = 4b + j//512, e = j%512.
// ---------------------------------------------------------------------------
__global__ __launch_bounds__(256) void k_out(
    const float* __restrict__ meanbuf, const float* __restrict__ maxbuf,
    const float* __restrict__ ow, const float* __restrict__ ob,
    float* __restrict__ out)
{
    __shared__ float pooled[4096];
    const int b = blockIdx.y;
    const int o = blockIdx.x * 256 + threadIdx.x;
    for (int j = threadIdx.x; j < 4096; j += 256) {
        float v;
        if (j < 2048) {
            v = meanbuf[(size_t)(4 * b + (j >> 9)) * EE + (j & 511)];
        } else {
            int jj = j - 2048;
            v = maxbuf[(size_t)(4 * b + (jj >> 9)) * EE + (jj & 511)];
        }
        pooled[j] = v;
    }
    __syncthreads();
    float acc = ob[o];
#pragma unroll 8
    for (int j = 0; j < 4096; ++j)
        acc = fmaf(pooled[j], ow[(size_t)j * 1024 + o], acc);
    out[(size_t)b * 1024 + o] = fmaxf(acc, 0.f);
}

// ---------------------------------------------------------------------------
extern "C" void kernel_launch(void* const* d_in, const int* in_sizes, int n_in,
                              void* d_out, int out_size, void* d_ws, size_t ws_size,
                              hipStream_t stream)
{
    const float* x1     = (const float*)d_in[0];
    const float* x2     = (const float*)d_in[1];
    const int*   x1_len = (const int*)d_in[2];
    const int*   x2_len = (const int*)d_in[3];
    const float* fw     = (const float*)d_in[4];
    const float* fb     = (const float*)d_in[5];
    const float* ow     = (const float*)d_in[6];
    const float* ob     = (const float*)d_in[7];

    float* out  = (float*)d_out;                       // [32, 1024]
    float* attn = out + (size_t)BATCH * 1024;          // [128, 512, 512]

    float* xatt    = (float*)d_ws;                     // [128, 512, 512] f32 (64 MB)
    float* meanbuf = xatt + (size_t)NB * LL * EE;      // [128, 512]
    float* maxbuf  = meanbuf + (size_t)NB * EE;        // [128, 512]

    k_scores<<<dim3(8, 8, NB), 256, 0, stream>>>(x1, x2, x1_len, x2_len, attn);
    k_softmax<<<dim3(NB * LL / 4), 256, 0, stream>>>(attn);
    k_pv<<<dim3(8, 8, NB), 256, 0, stream>>>(attn, x2, xatt);
    k_fuse<<<dim3(8, NB), 256, 0, stream>>>(x1, xatt, fw, fb, meanbuf, maxbuf);
    k_out<<<dim3(4, BATCH), 256, 0, stream>>>(meanbuf, maxbuf, ow, ob, out);
}

// Round 2
// 904.250 us; speedup vs baseline: 3.4810x; 3.4810x over previous
//
#include <hip/hip_runtime.h>
#include <cstddef>

// Problem constants (reference: B=32, NDOC=4, L=512, E=512)
#define BATCH 32
#define NB    128
#define LL    512
#define EE    512
#define SCALE 0.044194173824159216f
#define NEG_INF -1e9f

typedef __attribute__((ext_vector_type(4))) float f32x4;
typedef __attribute__((ext_vector_type(8))) short s16x8;          // 8 bf16 (4 VGPRs) MFMA frag
typedef __attribute__((ext_vector_type(4))) unsigned short u16x4;

__device__ __forceinline__ unsigned short f2b(float f) {          // f32 -> bf16 RNE
    unsigned u = __float_as_uint(f);
    u += 0x7FFFu + ((u >> 16) & 1u);
    return (unsigned short)(u >> 16);
}
__device__ __forceinline__ float b2f(unsigned short h) {
    return __uint_as_float(((unsigned)h) << 16);
}

// ---------------------------------------------------------------------------
// Converters: x1 -> bf16; x2 -> bf16 (row) + bf16 transposed; fw -> fw^T bf16
// ---------------------------------------------------------------------------
__global__ __launch_bounds__(256) void k_cvt_x1(
    const float* __restrict__ x1, unsigned short* __restrict__ x1bf)
{
    const size_t idx = (size_t)blockIdx.x * 256 + threadIdx.x;    // 4 elems each
    f32x4 v = *(const f32x4*)(x1 + idx * 4);
    u16x4 o = { f2b(v[0]), f2b(v[1]), f2b(v[2]), f2b(v[3]) };
    *(u16x4*)(x1bf + idx * 4) = o;
}

__global__ __launch_bounds__(256) void k_cvt_x2(
    const float* __restrict__ x2,
    unsigned short* __restrict__ x2bf, unsigned short* __restrict__ x2t)
{
    __shared__ float T[64][65];
    const int i = blockIdx.z, kb = blockIdx.y * 64, eb = blockIdx.x * 64;
    const float* src = x2 + (size_t)i * LL * EE;
    unsigned short* db = x2bf + (size_t)i * LL * EE;
    unsigned short* dt = x2t  + (size_t)i * LL * EE;
    const int t = threadIdx.x, r16 = t >> 4, c4 = (t & 15) * 4;
#pragma unroll
    for (int p = 0; p < 4; ++p) {
        int row = p * 16 + r16;
        f32x4 v = *(const f32x4*)(src + (size_t)(kb + row) * EE + eb + c4);
        T[row][c4] = v[0]; T[row][c4+1] = v[1]; T[row][c4+2] = v[2]; T[row][c4+3] = v[3];
        u16x4 o = { f2b(v[0]), f2b(v[1]), f2b(v[2]), f2b(v[3]) };
        *(u16x4*)(db + (size_t)(kb + row) * EE + eb + c4) = o;
    }
    __syncthreads();
#pragma unroll
    for (int p = 0; p < 4; ++p) {
        int erow = p * 16 + r16;
        u16x4 o = { f2b(T[c4][erow]), f2b(T[c4+1][erow]),
                    f2b(T[c4+2][erow]), f2b(T[c4+3][erow]) };
        *(u16x4*)(dt + (size_t)(eb + erow) * LL + kb + c4) = o;   // dt[e][k]=src[k][e]
    }
}

__global__ __launch_bounds__(256) void k_cvt_fw(
    const float* __restrict__ fw, unsigned short* __restrict__ fwt)
{
    __shared__ float T[64][65];
    const int jb = blockIdx.y * 64, eb = blockIdx.x * 64;
    const int t = threadIdx.x, r16 = t >> 4, c4 = (t & 15) * 4;
#pragma unroll
    for (int p = 0; p < 4; ++p) {
        int row = p * 16 + r16;                                   // j-row
        f32x4 v = *(const f32x4*)(fw + (size_t)(jb + row) * EE + eb + c4);
        T[row][c4] = v[0]; T[row][c4+1] = v[1]; T[row][c4+2] = v[2]; T[row][c4+3] = v[3];
    }
    __syncthreads();
#pragma unroll
    for (int p = 0; p < 4; ++p) {
        int erow = p * 16 + r16;
        u16x4 o = { f2b(T[c4][erow]), f2b(T[c4+1][erow]),
                    f2b(T[c4+2][erow]), f2b(T[c4+3][erow]) };
        *(u16x4*)(fwt + (size_t)(eb + erow) * 1024 + jb + c4) = o; // fwt[e][j]
    }
}

// ---------------------------------------------------------------------------
// K1: scores = mask(x1 @ x2^T * scale). bf16 MFMA, 128x128 tile, BK=32.
// NT layout: both operands K(=e)-contiguous. LDS row stride 40 shorts.
// ---------------------------------------------------------------------------
__global__ __launch_bounds__(256) void k_scores_mfma(
    const unsigned short* __restrict__ x1bf,
    const unsigned short* __restrict__ x2bf,
    const int* __restrict__ x1_len, const int* __restrict__ x2_len,
    float* __restrict__ attn)
{
    __shared__ unsigned short Al[128 * 40];
    __shared__ unsigned short Bl[128 * 40];
    const int i  = blockIdx.z;
    const int q0 = blockIdx.y * 128;
    const int k0 = blockIdx.x * 128;
    const unsigned short* Ag = x1bf + (size_t)(i & 31) * LL * EE;
    const unsigned short* Bg = x2bf + (size_t)i * LL * EE;
    const int t = threadIdx.x, lane = t & 63;
    const int w = t >> 6, wrow = w >> 1, wcol = w & 1;
    const int m = lane & 15, quad = lane >> 4;
    const int srow = t >> 1, shalf = (t & 1) * 16;

    f32x4 acc[4][4];
#pragma unroll
    for (int r = 0; r < 4; ++r)
#pragma unroll
        for (int c = 0; c < 4; ++c) acc[r][c] = (f32x4){0.f, 0.f, 0.f, 0.f};

    for (int e0 = 0; e0 < EE; e0 += 32) {
        s16x8 a0 = *(const s16x8*)(Ag + (size_t)(q0 + srow) * EE + e0 + shalf);
        s16x8 a1 = *(const s16x8*)(Ag + (size_t)(q0 + srow) * EE + e0 + shalf + 8);
        s16x8 b0 = *(const s16x8*)(Bg + (size_t)(k0 + srow) * EE + e0 + shalf);
        s16x8 b1 = *(const s16x8*)(Bg + (size_t)(k0 + srow) * EE + e0 + shalf + 8);
        __syncthreads();
        *(s16x8*)&Al[srow * 40 + shalf]     = a0;
        *(s16x8*)&Al[srow * 40 + shalf + 8] = a1;
        *(s16x8*)&Bl[srow * 40 + shalf]     = b0;
        *(s16x8*)&Bl[srow * 40 + shalf + 8] = b1;
        __syncthreads();
        s16x8 af[4], bfr[4];
#pragma unroll
        for (int rt = 0; rt < 4; ++rt)
            af[rt] = *(const s16x8*)&Al[(wrow * 64 + rt * 16 + m) * 40 + quad * 8];
#pragma unroll
        for (int ct = 0; ct < 4; ++ct)
            bfr[ct] = *(const s16x8*)&Bl[(wcol * 64 + ct * 16 + m) * 40 + quad * 8];
#pragma unroll
        for (int rt = 0; rt < 4; ++rt)
#pragma unroll
            for (int ct = 0; ct < 4; ++ct)
                acc[rt][ct] = __builtin_amdgcn_mfma_f32_16x16x32_bf16(
                    af[rt], bfr[ct], acc[rt][ct], 0, 0, 0);
    }

    const int qlen = x1_len[i & 31];
    const int klen = x2_len[i];
    float* op = attn + (size_t)i * LL * LL;
#pragma unroll
    for (int rt = 0; rt < 4; ++rt) {
#pragma unroll
        for (int reg = 0; reg < 4; ++reg) {
            const int q = q0 + wrow * 64 + rt * 16 + quad * 4 + reg;  // D row
            const bool qok = q < qlen;
#pragma unroll
            for (int ct = 0; ct < 4; ++ct) {
                const int k = k0 + wcol * 64 + ct * 16 + m;           // D col
                float v = (qok && k < klen) ? acc[rt][ct][reg] * SCALE : NEG_INF;
                op[(size_t)q * LL + k] = v;
            }
        }
    }
}

// ---------------------------------------------------------------------------
// K2: in-place row softmax (unchanged from round 0 — correct & cheap).
// ---------------------------------------------------------------------------
__global__ __launch_bounds__(256) void k_softmax(float* __restrict__ attn)
{
    const int row  = blockIdx.x * 4 + (threadIdx.x >> 6);
    const int lane = threadIdx.x & 63;
    float* p = attn + (size_t)row * LL + lane * 8;
    float4 v0 = *(float4*)p;
    float4 v1 = *(float4*)(p + 4);
    float mx = fmaxf(fmaxf(fmaxf(v0.x, v0.y), fmaxf(v0.z, v0.w)),
                     fmaxf(fmaxf(v1.x, v1.y), fmaxf(v1.z, v1.w)));
#pragma unroll
    for (int o = 32; o > 0; o >>= 1) mx = fmaxf(mx, __shfl_xor(mx, o));
    v0.x = __expf(v0.x - mx); v0.y = __expf(v0.y - mx);
    v0.z = __expf(v0.z - mx); v0.w = __expf(v0.w - mx);
    v1.x = __expf(v1.x - mx); v1.y = __expf(v1.y - mx);
    v1.z = __expf(v1.z - mx); v1.w = __expf(v1.w - mx);
    float s = v0.x + v0.y + v0.z + v0.w + v1.x + v1.y + v1.z + v1.w;
#pragma unroll
    for (int o = 32; o > 0; o >>= 1) s += __shfl_xor(s, o);
    const float inv = 1.0f / s;
    v0.x *= inv; v0.y *= inv; v0.z *= inv; v0.w *= inv;
    v1.x *= inv; v1.y *= inv; v1.z *= inv; v1.w *= inv;
    *(float4*)p = v0;
    *(float4*)(p + 4) = v1;
}

// ---------------------------------------------------------------------------
// K3: x1_att = attn @ x2 via MFMA (A = f32 attn, cvt-in-staging; B = x2^T).
// Epilogue materializes Cbuf[l][j] = [x1-att | x1*att] in bf16 for k_fuse.
// ---------------------------------------------------------------------------
__global__ __launch_bounds__(256) void k_pv_mfma(
    const float* __restrict__ attn,
    const unsigned short* __restrict__ x2t,
    const unsigned short* __restrict__ x1bf,
    unsigned short* __restrict__ Cbuf)
{
    __shared__ unsigned short Al[128 * 40];
    __shared__ unsigned short Bl[128 * 40];
    const int i  = blockIdx.z;
    const int q0 = blockIdx.y * 128;      // l rows
    const int e0 = blockIdx.x * 128;      // e cols
    const float* Ag = attn + (size_t)i * LL * LL;
    const unsigned short* Bg = x2t + (size_t)i * LL * EE;
    const int t = threadIdx.x, lane = t & 63;
    const int w = t >> 6, wrow = w >> 1, wcol = w & 1;
    const int m = lane & 15, quad = lane >> 4;
    const int srow = t >> 1, shalf = (t & 1) * 16;

    f32x4 acc[4][4];
#pragma unroll
    for (int r = 0; r < 4; ++r)
#pragma unroll
        for (int c = 0; c < 4; ++c) acc[r][c] = (f32x4){0.f, 0.f, 0.f, 0.f};

    for (int kk0 = 0; kk0 < LL; kk0 += 32) {
        const float* ap = Ag + (size_t)(q0 + srow) * LL + kk0 + shalf;
        f32x4 v0 = *(const f32x4*)(ap + 0);
        f32x4 v1 = *(const f32x4*)(ap + 4);
        f32x4 v2 = *(const f32x4*)(ap + 8);
        f32x4 v3 = *(const f32x4*)(ap + 12);
        s16x8 b0 = *(const s16x8*)(Bg + (size_t)(e0 + srow) * LL + kk0 + shalf);
        s16x8 b1 = *(const s16x8*)(Bg + (size_t)(e0 + srow) * LL + kk0 + shalf + 8);
        s16x8 pa0, pa1;
#pragma unroll
        for (int j = 0; j < 4; ++j) {
            pa0[j]     = (short)f2b(v0[j]);
            pa0[j + 4] = (short)f2b(v1[j]);
            pa1[j]     = (short)f2b(v2[j]);
            pa1[j + 4] = (short)f2b(v3[j]);
        }
        __syncthreads();
        *(s16x8*)&Al[srow * 40 + shalf]     = pa0;
        *(s16x8*)&Al[srow * 40 + shalf + 8] = pa1;
        *(s16x8*)&Bl[srow * 40 + shalf]     = b0;
        *(s16x8*)&Bl[srow * 40 + shalf + 8] = b1;
        __syncthreads();
        s16x8 af[4], bfr[4];
#pragma unroll
        for (int rt = 0; rt < 4; ++rt)
            af[rt] = *(const s16x8*)&Al[(wrow * 64 + rt * 16 + m) * 40 + quad * 8];
#pragma unroll
        for (int ct = 0; ct < 4; ++ct)
            bfr[ct] = *(const s16x8*)&Bl[(wcol * 64 + ct * 16 + m) * 40 + quad * 8];
#pragma unroll
        for (int rt = 0; rt < 4; ++rt)
#pragma unroll
            for (int ct = 0; ct < 4; ++ct)
                acc[rt][ct] = __builtin_amdgcn_mfma_f32_16x16x32_bf16(
                    af[rt], bfr[ct], acc[rt][ct], 0, 0, 0);
    }

    const unsigned short* x1p = x1bf + (size_t)(i & 31) * LL * EE;
    unsigned short* Cb = Cbuf + (size_t)i * LL * 1024;
#pragma unroll
    for (int rt = 0; rt < 4; ++rt) {
#pragma unroll
        for (int reg = 0; reg < 4; ++reg) {
            const int l = q0 + wrow * 64 + rt * 16 + quad * 4 + reg;
#pragma unroll
            for (int ct = 0; ct < 4; ++ct) {
                const int e = e0 + wcol * 64 + ct * 16 + m;
                float att = acc[rt][ct][reg];
                float xv  = b2f(x1p[(size_t)l * EE + e]);
                Cb[(size_t)l * 1024 + e]       = f2b(xv - att);
                Cb[(size_t)l * 1024 + 512 + e] = f2b(xv * att);
            }
        }
    }
}

// ---------------------------------------------------------------------------
// K4: fus = relu(Cbuf @ fw + b) with fused mean/max pooling over L.
// Pure bf16 MFMA GEMM: A = Cbuf[l][j] (j contig), B = fwt[e][j] (j contig).
// Grid (4 e-tiles, 128 i); each block loops 4 M-tiles of 128 l-rows.
// ---------------------------------------------------------------------------
__global__ __launch_bounds__(256) void k_fuse_mfma(
    const unsigned short* __restrict__ Cbuf,
    const unsigned short* __restrict__ fwt,
    const float* __restrict__ fb,
    float* __restrict__ meanbuf, float* __restrict__ maxbuf)
{
    __shared__ unsigned short Al[128 * 40];
    __shared__ unsigned short Bl[128 * 40];
    __shared__ float psum[2][128];
    __shared__ float pmax[2][128];
    const int i  = blockIdx.y;
    const int e0 = blockIdx.x * 128;
    const unsigned short* Ab = Cbuf + (size_t)i * LL * 1024;
    const int t = threadIdx.x, lane = t & 63;
    const int w = t >> 6, wrow = w >> 1, wcol = w & 1;
    const int m = lane & 15, quad = lane >> 4;
    const int srow = t >> 1, shalf = (t & 1) * 16;

    float bias[4];
#pragma unroll
    for (int ct = 0; ct < 4; ++ct) bias[ct] = fb[e0 + wcol * 64 + ct * 16 + m];
    float csum[4] = {0.f, 0.f, 0.f, 0.f};
    float cmax[4] = {-3e38f, -3e38f, -3e38f, -3e38f};

    for (int l0 = 0; l0 < LL; l0 += 128) {
        f32x4 acc[4][4];
#pragma unroll
        for (int r = 0; r < 4; ++r)
#pragma unroll
            for (int c = 0; c < 4; ++c) acc[r][c] = (f32x4){0.f, 0.f, 0.f, 0.f};

        for (int j0 = 0; j0 < 1024; j0 += 32) {
            s16x8 a0 = *(const s16x8*)(Ab + (size_t)(l0 + srow) * 1024 + j0 + shalf);
            s16x8 a1 = *(const s16x8*)(Ab + (size_t)(l0 + srow) * 1024 + j0 + shalf + 8);
            s16x8 b0 = *(const s16x8*)(fwt + (size_t)(e0 + srow) * 1024 + j0 + shalf);
            s16x8 b1 = *(const s16x8*)(fwt + (size_t)(e0 + srow) * 1024 + j0 + shalf + 8);
            __syncthreads();
            *(s16x8*)&Al[srow * 40 + shalf]     = a0;
            *(s16x8*)&Al[srow * 40 + shalf + 8] = a1;
            *(s16x8*)&Bl[srow * 40 + shalf]     = b0;
            *(s16x8*)&Bl[srow * 40 + shalf + 8] = b1;
            __syncthreads();
            s16x8 af[4], bfr[4];
#pragma unroll
            for (int rt = 0; rt < 4; ++rt)
                af[rt] = *(const s16x8*)&Al[(wrow * 64 + rt * 16 + m) * 40 + quad * 8];
#pragma unroll
            for (int ct = 0; ct < 4; ++ct)
                bfr[ct] = *(const s16x8*)&Bl[(wcol * 64 + ct * 16 + m) * 40 + quad * 8];
#pragma unroll
            for (int rt = 0; rt < 4; ++rt)
#pragma unroll
                for (int ct = 0; ct < 4; ++ct)
                    acc[rt][ct] = __builtin_amdgcn_mfma_f32_16x16x32_bf16(
                        af[rt], bfr[ct], acc[rt][ct], 0, 0, 0);
        }
        // relu + pool this M-tile (rows are distinct l's per lane)
#pragma unroll
        for (int rt = 0; rt < 4; ++rt)
#pragma unroll
            for (int reg = 0; reg < 4; ++reg)
#pragma unroll
                for (int ct = 0; ct < 4; ++ct) {
                    float f = fmaxf(acc[rt][ct][reg] + bias[ct], 0.f);
                    csum[ct] += f;
                    cmax[ct] = fmaxf(cmax[ct], f);
                }
    }
    // reduce across quads (lanes quad 0..3 hold same cols)
#pragma unroll
    for (int ct = 0; ct < 4; ++ct) {
        csum[ct] += __shfl_xor(csum[ct], 16);
        csum[ct] += __shfl_xor(csum[ct], 32);
        cmax[ct] = fmaxf(cmax[ct], __shfl_xor(cmax[ct], 16));
        cmax[ct] = fmaxf(cmax[ct], __shfl_xor(cmax[ct], 32));
    }
    if (quad == 0) {
#pragma unroll
        for (int ct = 0; ct < 4; ++ct) {
            psum[wrow][wcol * 64 + ct * 16 + m] = csum[ct];
            pmax[wrow][wcol * 64 + ct * 16 + m] = cmax[ct];
        }
    }
    __syncthreads();
    if (t < 128) {
        float s  = psum[0][t] + psum[1][t];
        float mx = fmaxf(pmax[0][t], pmax[1][t]);
        meanbuf[(size_t)i * EE + e0 + t] = s * (1.0f / 512.0f);
        maxbuf[(size_t)i * EE + e0 + t] = mx;
    }
}

// ---------------------------------------------------------------------------
// K5: out = relu(pooled @ out_w + out_b) (unchanged from round 0).
// ---------------------------------------------------------------------------
__global__ __launch_bounds__(256) void k_out(
    const float* __restrict__ meanbuf, const float* __restrict__ maxbuf,
    const float* __restrict__ ow, const float* __restrict__ ob,
    float* __restrict__ out)
{
    __shared__ float pooled[4096];
    const int b = blockIdx.y;
    const int o = blockIdx.x * 256 + threadIdx.x;
    for (int j = threadIdx.x; j < 4096; j += 256) {
        float v;
        if (j < 2048) {
            v = meanbuf[(size_t)(4 * b + (j >> 9)) * EE + (j & 511)];
        } else {
            int jj = j - 2048;
            v = maxbuf[(size_t)(4 * b + (jj >> 9)) * EE + (jj & 511)];
        }
        pooled[j] = v;
    }
    __syncthreads();
    float acc = ob[o];
#pragma unroll 8
    for (int j = 0; j < 4096; ++j)
        acc = fmaf(pooled[j], ow[(size_t)j * 1024 + o], acc);
    out[(size_t)b * 1024 + o] = fmaxf(acc, 0.f);
}

// ---------------------------------------------------------------------------
extern "C" void kernel_launch(void* const* d_in, const int* in_sizes, int n_in,
                              void* d_out, int out_size, void* d_ws, size_t ws_size,
                              hipStream_t stream)
{
    const float* x1     = (const float*)d_in[0];
    const float* x2     = (const float*)d_in[1];
    const int*   x1_len = (const int*)d_in[2];   // jax default x64-disabled -> int32
    const int*   x2_len = (const int*)d_in[3];
    const float* fw     = (const float*)d_in[4];
    const float* fb     = (const float*)d_in[5];
    const float* ow     = (const float*)d_in[6];
    const float* ob     = (const float*)d_in[7];

    float* out  = (float*)d_out;                  // [32, 1024]
    float* attn = out + (size_t)BATCH * 1024;     // [128, 512, 512] f32

    // workspace layout (~287 MB)
    char* wp = (char*)d_ws;
    unsigned short* x1bf = (unsigned short*)wp; wp += (size_t)BATCH * LL * EE * 2;
    unsigned short* x2bf = (unsigned short*)wp; wp += (size_t)NB * LL * EE * 2;
    unsigned short* x2t  = (unsigned short*)wp; wp += (size_t)NB * LL * EE * 2;
    unsigned short* Cbuf = (unsigned short*)wp; wp += (size_t)NB * LL * 1024 * 2;
    unsigned short* fwt  = (unsigned short*)wp; wp += (size_t)EE * 1024 * 2;
    float* meanbuf = (float*)wp; wp += (size_t)NB * EE * 4;
    float* maxbuf  = (float*)wp; wp += (size_t)NB * EE * 4;

    k_cvt_x1<<<dim3(BATCH * LL * EE / 4 / 256), 256, 0, stream>>>(x1, x1bf);
    k_cvt_x2<<<dim3(8, 8, NB), 256, 0, stream>>>(x2, x2bf, x2t);
    k_cvt_fw<<<dim3(8, 16), 256, 0, stream>>>(fw, fwt);
    k_scores_mfma<<<dim3(4, 4, NB), 256, 0, stream>>>(x1bf, x2bf, x1_len, x2_len, attn);
    k_softmax<<<dim3(NB * LL / 4), 256, 0, stream>>>(attn);
    k_pv_mfma<<<dim3(4, 4, NB), 256, 0, stream>>>(attn, x2t, x1bf, Cbuf);
    k_fuse_mfma<<<dim3(4, NB), 256, 0, stream>>>(Cbuf, fwt, fb, meanbuf, maxbuf);
    k_out<<<dim3(4, BATCH), 256, 0, stream>>>(meanbuf, maxbuf, ow, ob, out);
}

// Round 3
// 673.406 us; speedup vs baseline: 4.6743x; 1.3428x over previous
//
#include <hip/hip_runtime.h>
#include <cstddef>

// Problem constants (reference: B=32, NDOC=4, L=512, E=512)
#define BATCH 32
#define NB    128
#define LL    512
#define EE    512
#define SCALE 0.044194173824159216f
#define NEG_INF -1e9f

typedef __attribute__((ext_vector_type(4))) float f32x4;
typedef __attribute__((ext_vector_type(8))) short s16x8;          // 8 bf16 (4 VGPRs) MFMA frag
typedef __attribute__((ext_vector_type(4))) unsigned short u16x4;

__device__ __forceinline__ unsigned short f2b(float f) {          // f32 -> bf16 RNE
    unsigned u = __float_as_uint(f);
    u += 0x7FFFu + ((u >> 16) & 1u);
    return (unsigned short)(u >> 16);
}
__device__ __forceinline__ float b2f(unsigned short h) {
    return __uint_as_float(((unsigned)h) << 16);
}

// ---------------------------------------------------------------------------
// Converters: x1 -> bf16; x2 -> bf16 (row) + bf16 transposed; fw -> fw^T bf16
// ---------------------------------------------------------------------------
__global__ __launch_bounds__(256) void k_cvt_x1(
    const float* __restrict__ x1, unsigned short* __restrict__ x1bf)
{
    const size_t idx = (size_t)blockIdx.x * 256 + threadIdx.x;    // 4 elems each
    f32x4 v = *(const f32x4*)(x1 + idx * 4);
    u16x4 o = { f2b(v[0]), f2b(v[1]), f2b(v[2]), f2b(v[3]) };
    *(u16x4*)(x1bf + idx * 4) = o;
}

__global__ __launch_bounds__(256) void k_cvt_x2(
    const float* __restrict__ x2,
    unsigned short* __restrict__ x2bf, unsigned short* __restrict__ x2t)
{
    __shared__ float T[64][65];
    const int i = blockIdx.z, kb = blockIdx.y * 64, eb = blockIdx.x * 64;
    const float* src = x2 + (size_t)i * LL * EE;
    unsigned short* db = x2bf + (size_t)i * LL * EE;
    unsigned short* dt = x2t  + (size_t)i * LL * EE;
    const int t = threadIdx.x, r16 = t >> 4, c4 = (t & 15) * 4;
#pragma unroll
    for (int p = 0; p < 4; ++p) {
        int row = p * 16 + r16;
        f32x4 v = *(const f32x4*)(src + (size_t)(kb + row) * EE + eb + c4);
        T[row][c4] = v[0]; T[row][c4+1] = v[1]; T[row][c4+2] = v[2]; T[row][c4+3] = v[3];
        u16x4 o = { f2b(v[0]), f2b(v[1]), f2b(v[2]), f2b(v[3]) };
        *(u16x4*)(db + (size_t)(kb + row) * EE + eb + c4) = o;
    }
    __syncthreads();
#pragma unroll
    for (int p = 0; p < 4; ++p) {
        int erow = p * 16 + r16;
        u16x4 o = { f2b(T[c4][erow]), f2b(T[c4+1][erow]),
                    f2b(T[c4+2][erow]), f2b(T[c4+3][erow]) };
        *(u16x4*)(dt + (size_t)(eb + erow) * LL + kb + c4) = o;   // dt[e][k]=src[k][e]
    }
}

__global__ __launch_bounds__(256) void k_cvt_fw(
    const float* __restrict__ fw, unsigned short* __restrict__ fwt)
{
    __shared__ float T[64][65];
    const int jb = blockIdx.y * 64, eb = blockIdx.x * 64;
    const int t = threadIdx.x, r16 = t >> 4, c4 = (t & 15) * 4;
#pragma unroll
    for (int p = 0; p < 4; ++p) {
        int row = p * 16 + r16;                                   // j-row
        f32x4 v = *(const f32x4*)(fw + (size_t)(jb + row) * EE + eb + c4);
        T[row][c4] = v[0]; T[row][c4+1] = v[1]; T[row][c4+2] = v[2]; T[row][c4+3] = v[3];
    }
    __syncthreads();
#pragma unroll
    for (int p = 0; p < 4; ++p) {
        int erow = p * 16 + r16;
        u16x4 o = { f2b(T[c4][erow]), f2b(T[c4+1][erow]),
                    f2b(T[c4+2][erow]), f2b(T[c4+3][erow]) };
        *(u16x4*)(fwt + (size_t)(eb + erow) * 1024 + jb + c4) = o; // fwt[e][j]
    }
}

// ---------------------------------------------------------------------------
// K1: scores = mask(x1 @ x2^T * scale). bf16 MFMA, 128x128 tile, BK=32.
// NT layout: both operands K(=e)-contiguous. LDS row stride 40 shorts.
// ---------------------------------------------------------------------------
__global__ __launch_bounds__(256) void k_scores_mfma(
    const unsigned short* __restrict__ x1bf,
    const unsigned short* __restrict__ x2bf,
    const int* __restrict__ x1_len, const int* __restrict__ x2_len,
    float* __restrict__ attn)
{
    __shared__ unsigned short Al[128 * 40];
    __shared__ unsigned short Bl[128 * 40];
    const int i  = blockIdx.z;
    const int q0 = blockIdx.y * 128;
    const int k0 = blockIdx.x * 128;
    const unsigned short* Ag = x1bf + (size_t)(i & 31) * LL * EE;
    const unsigned short* Bg = x2bf + (size_t)i * LL * EE;
    const int t = threadIdx.x, lane = t & 63;
    const int w = t >> 6, wrow = w >> 1, wcol = w & 1;
    const int m = lane & 15, quad = lane >> 4;
    const int srow = t >> 1, shalf = (t & 1) * 16;

    f32x4 acc[4][4];
#pragma unroll
    for (int r = 0; r < 4; ++r)
#pragma unroll
        for (int c = 0; c < 4; ++c) acc[r][c] = (f32x4){0.f, 0.f, 0.f, 0.f};

    for (int e0 = 0; e0 < EE; e0 += 32) {
        s16x8 a0 = *(const s16x8*)(Ag + (size_t)(q0 + srow) * EE + e0 + shalf);
        s16x8 a1 = *(const s16x8*)(Ag + (size_t)(q0 + srow) * EE + e0 + shalf + 8);
        s16x8 b0 = *(const s16x8*)(Bg + (size_t)(k0 + srow) * EE + e0 + shalf);
        s16x8 b1 = *(const s16x8*)(Bg + (size_t)(k0 + srow) * EE + e0 + shalf + 8);
        __syncthreads();
        *(s16x8*)&Al[srow * 40 + shalf]     = a0;
        *(s16x8*)&Al[srow * 40 + shalf + 8] = a1;
        *(s16x8*)&Bl[srow * 40 + shalf]     = b0;
        *(s16x8*)&Bl[srow * 40 + shalf + 8] = b1;
        __syncthreads();
        s16x8 af[4], bfr[4];
#pragma unroll
        for (int rt = 0; rt < 4; ++rt)
            af[rt] = *(const s16x8*)&Al[(wrow * 64 + rt * 16 + m) * 40 + quad * 8];
#pragma unroll
        for (int ct = 0; ct < 4; ++ct)
            bfr[ct] = *(const s16x8*)&Bl[(wcol * 64 + ct * 16 + m) * 40 + quad * 8];
#pragma unroll
        for (int rt = 0; rt < 4; ++rt)
#pragma unroll
            for (int ct = 0; ct < 4; ++ct)
                acc[rt][ct] = __builtin_amdgcn_mfma_f32_16x16x32_bf16(
                    af[rt], bfr[ct], acc[rt][ct], 0, 0, 0);
    }

    const int qlen = x1_len[i & 31];
    const int klen = x2_len[i];
    float* op = attn + (size_t)i * LL * LL;
#pragma unroll
    for (int rt = 0; rt < 4; ++rt) {
#pragma unroll
        for (int reg = 0; reg < 4; ++reg) {
            const int q = q0 + wrow * 64 + rt * 16 + quad * 4 + reg;  // D row
            const bool qok = q < qlen;
#pragma unroll
            for (int ct = 0; ct < 4; ++ct) {
                const int k = k0 + wcol * 64 + ct * 16 + m;           // D col
                float v = (qok && k < klen) ? acc[rt][ct][reg] * SCALE : NEG_INF;
                op[(size_t)q * LL + k] = v;
            }
        }
    }
}

// ---------------------------------------------------------------------------
// K2: in-place row softmax. All-masked rows -> uniform 1/512, matching jax.
// ---------------------------------------------------------------------------
__global__ __launch_bounds__(256) void k_softmax(float* __restrict__ attn)
{
    const int row  = blockIdx.x * 4 + (threadIdx.x >> 6);
    const int lane = threadIdx.x & 63;
    float* p = attn + (size_t)row * LL + lane * 8;
    float4 v0 = *(float4*)p;
    float4 v1 = *(float4*)(p + 4);
    float mx = fmaxf(fmaxf(fmaxf(v0.x, v0.y), fmaxf(v0.z, v0.w)),
                     fmaxf(fmaxf(v1.x, v1.y), fmaxf(v1.z, v1.w)));
#pragma unroll
    for (int o = 32; o > 0; o >>= 1) mx = fmaxf(mx, __shfl_xor(mx, o));
    v0.x = __expf(v0.x - mx); v0.y = __expf(v0.y - mx);
    v0.z = __expf(v0.z - mx); v0.w = __expf(v0.w - mx);
    v1.x = __expf(v1.x - mx); v1.y = __expf(v1.y - mx);
    v1.z = __expf(v1.z - mx); v1.w = __expf(v1.w - mx);
    float s = v0.x + v0.y + v0.z + v0.w + v1.x + v1.y + v1.z + v1.w;
#pragma unroll
    for (int o = 32; o > 0; o >>= 1) s += __shfl_xor(s, o);
    const float inv = 1.0f / s;
    v0.x *= inv; v0.y *= inv; v0.z *= inv; v0.w *= inv;
    v1.x *= inv; v1.y *= inv; v1.z *= inv; v1.w *= inv;
    *(float4*)p = v0;
    *(float4*)(p + 4) = v1;
}

// ---------------------------------------------------------------------------
// K3: x1_att = attn @ x2 via MFMA (A = f32 attn, cvt-in-staging; B = x2^T).
// Epilogue materializes Cbuf[l][j] = [x1-att | x1*att] in bf16 for k_fuse.
// ---------------------------------------------------------------------------
__global__ __launch_bounds__(256) void k_pv_mfma(
    const float* __restrict__ attn,
    const unsigned short* __restrict__ x2t,
    const unsigned short* __restrict__ x1bf,
    unsigned short* __restrict__ Cbuf)
{
    __shared__ unsigned short Al[128 * 40];
    __shared__ unsigned short Bl[128 * 40];
    const int i  = blockIdx.z;
    const int q0 = blockIdx.y * 128;      // l rows
    const int e0 = blockIdx.x * 128;      // e cols
    const float* Ag = attn + (size_t)i * LL * LL;
    const unsigned short* Bg = x2t + (size_t)i * LL * EE;
    const int t = threadIdx.x, lane = t & 63;
    const int w = t >> 6, wrow = w >> 1, wcol = w & 1;
    const int m = lane & 15, quad = lane >> 4;
    const int srow = t >> 1, shalf = (t & 1) * 16;

    f32x4 acc[4][4];
#pragma unroll
    for (int r = 0; r < 4; ++r)
#pragma unroll
        for (int c = 0; c < 4; ++c) acc[r][c] = (f32x4){0.f, 0.f, 0.f, 0.f};

    for (int kk0 = 0; kk0 < LL; kk0 += 32) {
        const float* ap = Ag + (size_t)(q0 + srow) * LL + kk0 + shalf;
        f32x4 v0 = *(const f32x4*)(ap + 0);
        f32x4 v1 = *(const f32x4*)(ap + 4);
        f32x4 v2 = *(const f32x4*)(ap + 8);
        f32x4 v3 = *(const f32x4*)(ap + 12);
        s16x8 b0 = *(const s16x8*)(Bg + (size_t)(e0 + srow) * LL + kk0 + shalf);
        s16x8 b1 = *(const s16x8*)(Bg + (size_t)(e0 + srow) * LL + kk0 + shalf + 8);
        s16x8 pa0, pa1;
#pragma unroll
        for (int j = 0; j < 4; ++j) {
            pa0[j]     = (short)f2b(v0[j]);
            pa0[j + 4] = (short)f2b(v1[j]);
            pa1[j]     = (short)f2b(v2[j]);
            pa1[j + 4] = (short)f2b(v3[j]);
        }
        __syncthreads();
        *(s16x8*)&Al[srow * 40 + shalf]     = pa0;
        *(s16x8*)&Al[srow * 40 + shalf + 8] = pa1;
        *(s16x8*)&Bl[srow * 40 + shalf]     = b0;
        *(s16x8*)&Bl[srow * 40 + shalf + 8] = b1;
        __syncthreads();
        s16x8 af[4], bfr[4];
#pragma unroll
        for (int rt = 0; rt < 4; ++rt)
            af[rt] = *(const s16x8*)&Al[(wrow * 64 + rt * 16 + m) * 40 + quad * 8];
#pragma unroll
        for (int ct = 0; ct < 4; ++ct)
            bfr[ct] = *(const s16x8*)&Bl[(wcol * 64 + ct * 16 + m) * 40 + quad * 8];
#pragma unroll
        for (int rt = 0; rt < 4; ++rt)
#pragma unroll
            for (int ct = 0; ct < 4; ++ct)
                acc[rt][ct] = __builtin_amdgcn_mfma_f32_16x16x32_bf16(
                    af[rt], bfr[ct], acc[rt][ct], 0, 0, 0);
    }

    const unsigned short* x1p = x1bf + (size_t)(i & 31) * LL * EE;
    unsigned short* Cb = Cbuf + (size_t)i * LL * 1024;
#pragma unroll
    for (int rt = 0; rt < 4; ++rt) {
#pragma unroll
        for (int reg = 0; reg < 4; ++reg) {
            const int l = q0 + wrow * 64 + rt * 16 + quad * 4 + reg;
#pragma unroll
            for (int ct = 0; ct < 4; ++ct) {
                const int e = e0 + wcol * 64 + ct * 16 + m;
                float att = acc[rt][ct][reg];
                float xv  = b2f(x1p[(size_t)l * EE + e]);
                Cb[(size_t)l * 1024 + e]       = f2b(xv - att);
                Cb[(size_t)l * 1024 + 512 + e] = f2b(xv * att);
            }
        }
    }
}

// ---------------------------------------------------------------------------
// K4: fus = relu(Cbuf @ fw + b) with fused mean/max pooling over L.
// ---------------------------------------------------------------------------
__global__ __launch_bounds__(256) void k_fuse_mfma(
    const unsigned short* __restrict__ Cbuf,
    const unsigned short* __restrict__ fwt,
    const float* __restrict__ fb,
    float* __restrict__ meanbuf, float* __restrict__ maxbuf)
{
    __shared__ unsigned short Al[128 * 40];
    __shared__ unsigned short Bl[128 * 40];
    __shared__ float psum[2][128];
    __shared__ float pmax[2][128];
    const int i  = blockIdx.y;
    const int e0 = blockIdx.x * 128;
    const unsigned short* Ab = Cbuf + (size_t)i * LL * 1024;
    const int t = threadIdx.x, lane = t & 63;
    const int w = t >> 6, wrow = w >> 1, wcol = w & 1;
    const int m = lane & 15, quad = lane >> 4;
    const int srow = t >> 1, shalf = (t & 1) * 16;

    float bias[4];
#pragma unroll
    for (int ct = 0; ct < 4; ++ct) bias[ct] = fb[e0 + wcol * 64 + ct * 16 + m];
    float csum[4] = {0.f, 0.f, 0.f, 0.f};
    float cmax[4] = {-3e38f, -3e38f, -3e38f, -3e38f};

    for (int l0 = 0; l0 < LL; l0 += 128) {
        f32x4 acc[4][4];
#pragma unroll
        for (int r = 0; r < 4; ++r)
#pragma unroll
            for (int c = 0; c < 4; ++c) acc[r][c] = (f32x4){0.f, 0.f, 0.f, 0.f};

        for (int j0 = 0; j0 < 1024; j0 += 32) {
            s16x8 a0 = *(const s16x8*)(Ab + (size_t)(l0 + srow) * 1024 + j0 + shalf);
            s16x8 a1 = *(const s16x8*)(Ab + (size_t)(l0 + srow) * 1024 + j0 + shalf + 8);
            s16x8 b0 = *(const s16x8*)(fwt + (size_t)(e0 + srow) * 1024 + j0 + shalf);
            s16x8 b1 = *(const s16x8*)(fwt + (size_t)(e0 + srow) * 1024 + j0 + shalf + 8);
            __syncthreads();
            *(s16x8*)&Al[srow * 40 + shalf]     = a0;
            *(s16x8*)&Al[srow * 40 + shalf + 8] = a1;
            *(s16x8*)&Bl[srow * 40 + shalf]     = b0;
            *(s16x8*)&Bl[srow * 40 + shalf + 8] = b1;
            __syncthreads();
            s16x8 af[4], bfr[4];
#pragma unroll
            for (int rt = 0; rt < 4; ++rt)
                af[rt] = *(const s16x8*)&Al[(wrow * 64 + rt * 16 + m) * 40 + quad * 8];
#pragma unroll
            for (int ct = 0; ct < 4; ++ct)
                bfr[ct] = *(const s16x8*)&Bl[(wcol * 64 + ct * 16 + m) * 40 + quad * 8];
#pragma unroll
            for (int rt = 0; rt < 4; ++rt)
#pragma unroll
                for (int ct = 0; ct < 4; ++ct)
                    acc[rt][ct] = __builtin_amdgcn_mfma_f32_16x16x32_bf16(
                        af[rt], bfr[ct], acc[rt][ct], 0, 0, 0);
        }
#pragma unroll
        for (int rt = 0; rt < 4; ++rt)
#pragma unroll
            for (int reg = 0; reg < 4; ++reg)
#pragma unroll
                for (int ct = 0; ct < 4; ++ct) {
                    float f = fmaxf(acc[rt][ct][reg] + bias[ct], 0.f);
                    csum[ct] += f;
                    cmax[ct] = fmaxf(cmax[ct], f);
                }
    }
#pragma unroll
    for (int ct = 0; ct < 4; ++ct) {
        csum[ct] += __shfl_xor(csum[ct], 16);
        csum[ct] += __shfl_xor(csum[ct], 32);
        cmax[ct] = fmaxf(cmax[ct], __shfl_xor(cmax[ct], 16));
        cmax[ct] = fmaxf(cmax[ct], __shfl_xor(cmax[ct], 32));
    }
    if (quad == 0) {
#pragma unroll
        for (int ct = 0; ct < 4; ++ct) {
            psum[wrow][wcol * 64 + ct * 16 + m] = csum[ct];
            pmax[wrow][wcol * 64 + ct * 16 + m] = cmax[ct];
        }
    }
    __syncthreads();
    if (t < 128) {
        float s  = psum[0][t] + psum[1][t];
        float mx = fmaxf(pmax[0][t], pmax[1][t]);
        meanbuf[(size_t)i * EE + e0 + t] = s * (1.0f / 512.0f);
        maxbuf[(size_t)i * EE + e0 + t] = mx;
    }
}

// ---------------------------------------------------------------------------
// K5a: split-K partial GEMM for the output head.
// grid (16 kchunks, 32 b), 256 threads; thread owns outputs 4t..4t+3.
// partial[kc][b][o] = sum_{j in chunk} pooled[b][j] * ow[j][o]
// ---------------------------------------------------------------------------
__global__ __launch_bounds__(256) void k_out_split(
    const float* __restrict__ meanbuf, const float* __restrict__ maxbuf,
    const float* __restrict__ ow, float* __restrict__ partial)
{
    __shared__ float ps[256];
    const int kc = blockIdx.x;
    const int b  = blockIdx.y;
    const int t  = threadIdx.x;
    const int j  = kc * 256 + t;
    float v;
    if (j < 2048) {
        v = meanbuf[(size_t)(4 * b + (j >> 9)) * EE + (j & 511)];
    } else {
        int jj = j - 2048;
        v = maxbuf[(size_t)(4 * b + (jj >> 9)) * EE + (jj & 511)];
    }
    ps[t] = v;
    __syncthreads();
    f32x4 acc = {0.f, 0.f, 0.f, 0.f};
    const float* wp = ow + (size_t)kc * 256 * 1024 + t * 4;
#pragma unroll 8
    for (int jj = 0; jj < 256; ++jj) {
        f32x4 w4 = *(const f32x4*)(wp + (size_t)jj * 1024);
        float p = ps[jj];
        acc[0] = fmaf(p, w4[0], acc[0]);
        acc[1] = fmaf(p, w4[1], acc[1]);
        acc[2] = fmaf(p, w4[2], acc[2]);
        acc[3] = fmaf(p, w4[3], acc[3]);
    }
    *(f32x4*)(partial + ((size_t)kc * 32 + b) * 1024 + t * 4) = acc;
}

// ---------------------------------------------------------------------------
// K5b: final reduce over 16 K-chunks + bias + relu.
// ---------------------------------------------------------------------------
__global__ __launch_bounds__(256) void k_out_final(
    const float* __restrict__ partial, const float* __restrict__ ob,
    float* __restrict__ out)
{
    const int idx = blockIdx.x * 256 + threadIdx.x;   // 0..32767
    const int b = idx >> 10, o = idx & 1023;
    float s = ob[o];
#pragma unroll
    for (int kc = 0; kc < 16; ++kc)
        s += partial[((size_t)kc * 32 + b) * 1024 + o];
    out[idx] = fmaxf(s, 0.f);
}

// ---------------------------------------------------------------------------
extern "C" void kernel_launch(void* const* d_in, const int* in_sizes, int n_in,
                              void* d_out, int out_size, void* d_ws, size_t ws_size,
                              hipStream_t stream)
{
    const float* x1     = (const float*)d_in[0];
    const float* x2     = (const float*)d_in[1];
    const int*   x1_len = (const int*)d_in[2];
    const int*   x2_len = (const int*)d_in[3];
    const float* fw     = (const float*)d_in[4];
    const float* fb     = (const float*)d_in[5];
    const float* ow     = (const float*)d_in[6];
    const float* ob     = (const float*)d_in[7];

    float* out  = (float*)d_out;                  // [32, 1024]
    float* attn = out + (size_t)BATCH * 1024;     // [128, 512, 512] f32

    // workspace layout (~289 MB)
    char* wp = (char*)d_ws;
    unsigned short* x1bf = (unsigned short*)wp; wp += (size_t)BATCH * LL * EE * 2;
    unsigned short* x2bf = (unsigned short*)wp; wp += (size_t)NB * LL * EE * 2;
    unsigned short* x2t  = (unsigned short*)wp; wp += (size_t)NB * LL * EE * 2;
    unsigned short* Cbuf = (unsigned short*)wp; wp += (size_t)NB * LL * 1024 * 2;
    unsigned short* fwt  = (unsigned short*)wp; wp += (size_t)EE * 1024 * 2;
    float* meanbuf = (float*)wp; wp += (size_t)NB * EE * 4;
    float* maxbuf  = (float*)wp; wp += (size_t)NB * EE * 4;
    float* partial = (float*)wp; wp += (size_t)16 * BATCH * 1024 * 4;

    k_cvt_x1<<<dim3(BATCH * LL * EE / 4 / 256), 256, 0, stream>>>(x1, x1bf);
    k_cvt_x2<<<dim3(8, 8, NB), 256, 0, stream>>>(x2, x2bf, x2t);
    k_cvt_fw<<<dim3(8, 16), 256, 0, stream>>>(fw, fwt);
    k_scores_mfma<<<dim3(4, 4, NB), 256, 0, stream>>>(x1bf, x2bf, x1_len, x2_len, attn);
    k_softmax<<<dim3(NB * LL / 4), 256, 0, stream>>>(attn);
    k_pv_mfma<<<dim3(4, 4, NB), 256, 0, stream>>>(attn, x2t, x1bf, Cbuf);
    k_fuse_mfma<<<dim3(4, NB), 256, 0, stream>>>(Cbuf, fwt, fb, meanbuf, maxbuf);
    k_out_split<<<dim3(16, BATCH), 256, 0, stream>>>(meanbuf, maxbuf, ow, partial);
    k_out_final<<<dim3(BATCH * 1024 / 256), 256, 0, stream>>>(partial, ob, out);
}

// Round 4
// 660.408 us; speedup vs baseline: 4.7663x; 1.0197x over previous
//
#include <hip/hip_runtime.h>
#include <cstddef>

// Problem constants (reference: B=32, NDOC=4, L=512, E=512)
#define BATCH 32
#define NB    128
#define LL    512
#define EE    512
#define SCALE 0.044194173824159216f
#define NEG_INF -1e9f

typedef __attribute__((ext_vector_type(4))) float f32x4;
typedef __attribute__((ext_vector_type(8))) short s16x8;          // 8 bf16 (4 VGPRs) MFMA frag
typedef __attribute__((ext_vector_type(4))) unsigned short u16x4;

__device__ __forceinline__ unsigned short f2b(float f) {          // f32 -> bf16 RNE
    unsigned u = __float_as_uint(f);
    u += 0x7FFFu + ((u >> 16) & 1u);
    return (unsigned short)(u >> 16);
}
__device__ __forceinline__ float b2f(unsigned short h) {
    return __uint_as_float(((unsigned)h) << 16);
}

// ---------------------------------------------------------------------------
// Converters: x1 -> bf16; x2 -> bf16 (row) + bf16 transposed; fw -> fw^T bf16
// ---------------------------------------------------------------------------
__global__ __launch_bounds__(256) void k_cvt_x1(
    const float* __restrict__ x1, unsigned short* __restrict__ x1bf)
{
    const size_t idx = (size_t)blockIdx.x * 256 + threadIdx.x;
    f32x4 v = *(const f32x4*)(x1 + idx * 4);
    u16x4 o = { f2b(v[0]), f2b(v[1]), f2b(v[2]), f2b(v[3]) };
    *(u16x4*)(x1bf + idx * 4) = o;
}

__global__ __launch_bounds__(256) void k_cvt_x2(
    const float* __restrict__ x2,
    unsigned short* __restrict__ x2bf, unsigned short* __restrict__ x2t)
{
    __shared__ float T[64][65];
    const int i = blockIdx.z, kb = blockIdx.y * 64, eb = blockIdx.x * 64;
    const float* src = x2 + (size_t)i * LL * EE;
    unsigned short* db = x2bf + (size_t)i * LL * EE;
    unsigned short* dt = x2t  + (size_t)i * LL * EE;
    const int t = threadIdx.x, r16 = t >> 4, c4 = (t & 15) * 4;
#pragma unroll
    for (int p = 0; p < 4; ++p) {
        int row = p * 16 + r16;
        f32x4 v = *(const f32x4*)(src + (size_t)(kb + row) * EE + eb + c4);
        T[row][c4] = v[0]; T[row][c4+1] = v[1]; T[row][c4+2] = v[2]; T[row][c4+3] = v[3];
        u16x4 o = { f2b(v[0]), f2b(v[1]), f2b(v[2]), f2b(v[3]) };
        *(u16x4*)(db + (size_t)(kb + row) * EE + eb + c4) = o;
    }
    __syncthreads();
#pragma unroll
    for (int p = 0; p < 4; ++p) {
        int erow = p * 16 + r16;
        u16x4 o = { f2b(T[c4][erow]), f2b(T[c4+1][erow]),
                    f2b(T[c4+2][erow]), f2b(T[c4+3][erow]) };
        *(u16x4*)(dt + (size_t)(eb + erow) * LL + kb + c4) = o;   // dt[e][k]=src[k][e]
    }
}

__global__ __launch_bounds__(256) void k_cvt_fw(
    const float* __restrict__ fw, unsigned short* __restrict__ fwt)
{
    __shared__ float T[64][65];
    const int jb = blockIdx.y * 64, eb = blockIdx.x * 64;
    const int t = threadIdx.x, r16 = t >> 4, c4 = (t & 15) * 4;
#pragma unroll
    for (int p = 0; p < 4; ++p) {
        int row = p * 16 + r16;
        f32x4 v = *(const f32x4*)(fw + (size_t)(jb + row) * EE + eb + c4);
        T[row][c4] = v[0]; T[row][c4+1] = v[1]; T[row][c4+2] = v[2]; T[row][c4+3] = v[3];
    }
    __syncthreads();
#pragma unroll
    for (int p = 0; p < 4; ++p) {
        int erow = p * 16 + r16;
        u16x4 o = { f2b(T[c4][erow]), f2b(T[c4+1][erow]),
                    f2b(T[c4+2][erow]), f2b(T[c4+3][erow]) };
        *(u16x4*)(fwt + (size_t)(eb + erow) * 1024 + jb + c4) = o; // fwt[e][j]
    }
}

// ---------------------------------------------------------------------------
// K1: scores = mask(x1 @ x2^T * scale). bf16 MFMA, 128x128 tile, BK=32.
// XCD swizzle: grid (128,16), x=i so all 16 tile-blocks of batch i share an
// XCD (flat id = i + y*128, 128 % 8 == 0) -> x2bf[i]/x1bf strips hit L2.
// ---------------------------------------------------------------------------
__global__ __launch_bounds__(256) void k_scores_mfma(
    const unsigned short* __restrict__ x1bf,
    const unsigned short* __restrict__ x2bf,
    const int* __restrict__ x1_len, const int* __restrict__ x2_len,
    float* __restrict__ attn)
{
    __shared__ unsigned short Al[128 * 40];
    __shared__ unsigned short Bl[128 * 40];
    const int i  = blockIdx.x;
    const int q0 = (blockIdx.y >> 2) * 128;
    const int k0 = (blockIdx.y & 3) * 128;
    const unsigned short* Ag = x1bf + (size_t)(i & 31) * LL * EE;
    const unsigned short* Bg = x2bf + (size_t)i * LL * EE;
    const int t = threadIdx.x, lane = t & 63;
    const int w = t >> 6, wrow = w >> 1, wcol = w & 1;
    const int m = lane & 15, quad = lane >> 4;
    const int srow = t >> 1, shalf = (t & 1) * 16;

    f32x4 acc[4][4];
#pragma unroll
    for (int r = 0; r < 4; ++r)
#pragma unroll
        for (int c = 0; c < 4; ++c) acc[r][c] = (f32x4){0.f, 0.f, 0.f, 0.f};

    for (int e0 = 0; e0 < EE; e0 += 32) {
        s16x8 a0 = *(const s16x8*)(Ag + (size_t)(q0 + srow) * EE + e0 + shalf);
        s16x8 a1 = *(const s16x8*)(Ag + (size_t)(q0 + srow) * EE + e0 + shalf + 8);
        s16x8 b0 = *(const s16x8*)(Bg + (size_t)(k0 + srow) * EE + e0 + shalf);
        s16x8 b1 = *(const s16x8*)(Bg + (size_t)(k0 + srow) * EE + e0 + shalf + 8);
        __syncthreads();
        *(s16x8*)&Al[srow * 40 + shalf]     = a0;
        *(s16x8*)&Al[srow * 40 + shalf + 8] = a1;
        *(s16x8*)&Bl[srow * 40 + shalf]     = b0;
        *(s16x8*)&Bl[srow * 40 + shalf + 8] = b1;
        __syncthreads();
        s16x8 af[4], bfr[4];
#pragma unroll
        for (int rt = 0; rt < 4; ++rt)
            af[rt] = *(const s16x8*)&Al[(wrow * 64 + rt * 16 + m) * 40 + quad * 8];
#pragma unroll
        for (int ct = 0; ct < 4; ++ct)
            bfr[ct] = *(const s16x8*)&Bl[(wcol * 64 + ct * 16 + m) * 40 + quad * 8];
#pragma unroll
        for (int rt = 0; rt < 4; ++rt)
#pragma unroll
            for (int ct = 0; ct < 4; ++ct)
                acc[rt][ct] = __builtin_amdgcn_mfma_f32_16x16x32_bf16(
                    af[rt], bfr[ct], acc[rt][ct], 0, 0, 0);
    }

    const int qlen = x1_len[i & 31];
    const int klen = x2_len[i];
    float* op = attn + (size_t)i * LL * LL;
#pragma unroll
    for (int rt = 0; rt < 4; ++rt) {
#pragma unroll
        for (int reg = 0; reg < 4; ++reg) {
            const int q = q0 + wrow * 64 + rt * 16 + quad * 4 + reg;
            const bool qok = q < qlen;
#pragma unroll
            for (int ct = 0; ct < 4; ++ct) {
                const int k = k0 + wcol * 64 + ct * 16 + m;
                float v = (qok && k < klen) ? acc[rt][ct][reg] * SCALE : NEG_INF;
                op[(size_t)q * LL + k] = v;
            }
        }
    }
}

// ---------------------------------------------------------------------------
// K2: in-place row softmax; also emits a bf16 copy for the PV GEMM.
// ---------------------------------------------------------------------------
__global__ __launch_bounds__(256) void k_softmax(
    float* __restrict__ attn, unsigned short* __restrict__ attnbf)
{
    const int row  = blockIdx.x * 4 + (threadIdx.x >> 6);
    const int lane = threadIdx.x & 63;
    float* p = attn + (size_t)row * LL + lane * 8;
    float4 v0 = *(float4*)p;
    float4 v1 = *(float4*)(p + 4);
    float mx = fmaxf(fmaxf(fmaxf(v0.x, v0.y), fmaxf(v0.z, v0.w)),
                     fmaxf(fmaxf(v1.x, v1.y), fmaxf(v1.z, v1.w)));
#pragma unroll
    for (int o = 32; o > 0; o >>= 1) mx = fmaxf(mx, __shfl_xor(mx, o));
    v0.x = __expf(v0.x - mx); v0.y = __expf(v0.y - mx);
    v0.z = __expf(v0.z - mx); v0.w = __expf(v0.w - mx);
    v1.x = __expf(v1.x - mx); v1.y = __expf(v1.y - mx);
    v1.z = __expf(v1.z - mx); v1.w = __expf(v1.w - mx);
    float s = v0.x + v0.y + v0.z + v0.w + v1.x + v1.y + v1.z + v1.w;
#pragma unroll
    for (int o = 32; o > 0; o >>= 1) s += __shfl_xor(s, o);
    const float inv = 1.0f / s;
    v0.x *= inv; v0.y *= inv; v0.z *= inv; v0.w *= inv;
    v1.x *= inv; v1.y *= inv; v1.z *= inv; v1.w *= inv;
    *(float4*)p = v0;
    *(float4*)(p + 4) = v1;
    unsigned short* pb = attnbf + (size_t)row * LL + lane * 8;
    u16x4 o0 = { f2b(v0.x), f2b(v0.y), f2b(v0.z), f2b(v0.w) };
    u16x4 o1 = { f2b(v1.x), f2b(v1.y), f2b(v1.z), f2b(v1.w) };
    *(u16x4*)pb       = o0;
    *(u16x4*)(pb + 4) = o1;
}

// ---------------------------------------------------------------------------
// K3: x1_att = attn @ x2 (A = bf16 attnbf — no f32 repack; B = x2^T).
// Epilogue materializes Cbuf[l][j] = [x1-att | x1*att] bf16 for k_fuse.
// XCD swizzle: grid (128,16), x=i.
// ---------------------------------------------------------------------------
__global__ __launch_bounds__(256) void k_pv_mfma(
    const unsigned short* __restrict__ attnbf,
    const unsigned short* __restrict__ x2t,
    const unsigned short* __restrict__ x1bf,
    unsigned short* __restrict__ Cbuf)
{
    __shared__ unsigned short Al[128 * 40];
    __shared__ unsigned short Bl[128 * 40];
    const int i  = blockIdx.x;
    const int q0 = (blockIdx.y >> 2) * 128;   // l rows
    const int e0 = (blockIdx.y & 3) * 128;    // e cols
    const unsigned short* Ag = attnbf + (size_t)i * LL * LL;
    const unsigned short* Bg = x2t   + (size_t)i * LL * EE;
    const int t = threadIdx.x, lane = t & 63;
    const int w = t >> 6, wrow = w >> 1, wcol = w & 1;
    const int m = lane & 15, quad = lane >> 4;
    const int srow = t >> 1, shalf = (t & 1) * 16;

    f32x4 acc[4][4];
#pragma unroll
    for (int r = 0; r < 4; ++r)
#pragma unroll
        for (int c = 0; c < 4; ++c) acc[r][c] = (f32x4){0.f, 0.f, 0.f, 0.f};

    for (int kk0 = 0; kk0 < LL; kk0 += 32) {
        s16x8 a0 = *(const s16x8*)(Ag + (size_t)(q0 + srow) * LL + kk0 + shalf);
        s16x8 a1 = *(const s16x8*)(Ag + (size_t)(q0 + srow) * LL + kk0 + shalf + 8);
        s16x8 b0 = *(const s16x8*)(Bg + (size_t)(e0 + srow) * LL + kk0 + shalf);
        s16x8 b1 = *(const s16x8*)(Bg + (size_t)(e0 + srow) * LL + kk0 + shalf + 8);
        __syncthreads();
        *(s16x8*)&Al[srow * 40 + shalf]     = a0;
        *(s16x8*)&Al[srow * 40 + shalf + 8] = a1;
        *(s16x8*)&Bl[srow * 40 + shalf]     = b0;
        *(s16x8*)&Bl[srow * 40 + shalf + 8] = b1;
        __syncthreads();
        s16x8 af[4], bfr[4];
#pragma unroll
        for (int rt = 0; rt < 4; ++rt)
            af[rt] = *(const s16x8*)&Al[(wrow * 64 + rt * 16 + m) * 40 + quad * 8];
#pragma unroll
        for (int ct = 0; ct < 4; ++ct)
            bfr[ct] = *(const s16x8*)&Bl[(wcol * 64 + ct * 16 + m) * 40 + quad * 8];
#pragma unroll
        for (int rt = 0; rt < 4; ++rt)
#pragma unroll
            for (int ct = 0; ct < 4; ++ct)
                acc[rt][ct] = __builtin_amdgcn_mfma_f32_16x16x32_bf16(
                    af[rt], bfr[ct], acc[rt][ct], 0, 0, 0);
    }

    const unsigned short* x1p = x1bf + (size_t)(i & 31) * LL * EE;
    unsigned short* Cb = Cbuf + (size_t)i * LL * 1024;
#pragma unroll
    for (int rt = 0; rt < 4; ++rt) {
#pragma unroll
        for (int reg = 0; reg < 4; ++reg) {
            const int l = q0 + wrow * 64 + rt * 16 + quad * 4 + reg;
#pragma unroll
            for (int ct = 0; ct < 4; ++ct) {
                const int e = e0 + wcol * 64 + ct * 16 + m;
                float att = acc[rt][ct][reg];
                float xv  = b2f(x1p[(size_t)l * EE + e]);
                Cb[(size_t)l * 1024 + e]       = f2b(xv - att);
                Cb[(size_t)l * 1024 + 512 + e] = f2b(xv * att);
            }
        }
    }
}

// ---------------------------------------------------------------------------
// K4: fus = relu(Cbuf @ fw + b) with per-l-tile mean/max pooling partials.
// l-tiles moved into the grid: (128,16) = 2048 blocks (x=i for XCD locality;
// y = lt*4 + e-tile). Partials reduced for free in k_out_split.
// ---------------------------------------------------------------------------
__global__ __launch_bounds__(256) void k_fuse_mfma(
    const unsigned short* __restrict__ Cbuf,
    const unsigned short* __restrict__ fwt,
    const float* __restrict__ fb,
    float* __restrict__ pmean, float* __restrict__ pmax)
{
    __shared__ unsigned short Al[128 * 40];
    __shared__ unsigned short Bl[128 * 40];
    __shared__ float psum[2][128];
    __shared__ float pmx[2][128];
    const int i  = blockIdx.x;
    const int lt = blockIdx.y >> 2;
    const int e0 = (blockIdx.y & 3) * 128;
    const unsigned short* Ab = Cbuf + ((size_t)i * LL + lt * 128) * 1024;
    const int t = threadIdx.x, lane = t & 63;
    const int w = t >> 6, wrow = w >> 1, wcol = w & 1;
    const int m = lane & 15, quad = lane >> 4;
    const int srow = t >> 1, shalf = (t & 1) * 16;

    float bias[4];
#pragma unroll
    for (int ct = 0; ct < 4; ++ct) bias[ct] = fb[e0 + wcol * 64 + ct * 16 + m];
    float csum[4] = {0.f, 0.f, 0.f, 0.f};
    float cmax[4] = {-3e38f, -3e38f, -3e38f, -3e38f};

    f32x4 acc[4][4];
#pragma unroll
    for (int r = 0; r < 4; ++r)
#pragma unroll
        for (int c = 0; c < 4; ++c) acc[r][c] = (f32x4){0.f, 0.f, 0.f, 0.f};

    for (int j0 = 0; j0 < 1024; j0 += 32) {
        s16x8 a0 = *(const s16x8*)(Ab + (size_t)srow * 1024 + j0 + shalf);
        s16x8 a1 = *(const s16x8*)(Ab + (size_t)srow * 1024 + j0 + shalf + 8);
        s16x8 b0 = *(const s16x8*)(fwt + (size_t)(e0 + srow) * 1024 + j0 + shalf);
        s16x8 b1 = *(const s16x8*)(fwt + (size_t)(e0 + srow) * 1024 + j0 + shalf + 8);
        __syncthreads();
        *(s16x8*)&Al[srow * 40 + shalf]     = a0;
        *(s16x8*)&Al[srow * 40 + shalf + 8] = a1;
        *(s16x8*)&Bl[srow * 40 + shalf]     = b0;
        *(s16x8*)&Bl[srow * 40 + shalf + 8] = b1;
        __syncthreads();
        s16x8 af[4], bfr[4];
#pragma unroll
        for (int rt = 0; rt < 4; ++rt)
            af[rt] = *(const s16x8*)&Al[(wrow * 64 + rt * 16 + m) * 40 + quad * 8];
#pragma unroll
        for (int ct = 0; ct < 4; ++ct)
            bfr[ct] = *(const s16x8*)&Bl[(wcol * 64 + ct * 16 + m) * 40 + quad * 8];
#pragma unroll
        for (int rt = 0; rt < 4; ++rt)
#pragma unroll
            for (int ct = 0; ct < 4; ++ct)
                acc[rt][ct] = __builtin_amdgcn_mfma_f32_16x16x32_bf16(
                    af[rt], bfr[ct], acc[rt][ct], 0, 0, 0);
    }
#pragma unroll
    for (int rt = 0; rt < 4; ++rt)
#pragma unroll
        for (int reg = 0; reg < 4; ++reg)
#pragma unroll
            for (int ct = 0; ct < 4; ++ct) {
                float f = fmaxf(acc[rt][ct][reg] + bias[ct], 0.f);
                csum[ct] += f;
                cmax[ct] = fmaxf(cmax[ct], f);
            }
#pragma unroll
    for (int ct = 0; ct < 4; ++ct) {
        csum[ct] += __shfl_xor(csum[ct], 16);
        csum[ct] += __shfl_xor(csum[ct], 32);
        cmax[ct] = fmaxf(cmax[ct], __shfl_xor(cmax[ct], 16));
        cmax[ct] = fmaxf(cmax[ct], __shfl_xor(cmax[ct], 32));
    }
    if (quad == 0) {
#pragma unroll
        for (int ct = 0; ct < 4; ++ct) {
            psum[wrow][wcol * 64 + ct * 16 + m] = csum[ct];
            pmx[wrow][wcol * 64 + ct * 16 + m] = cmax[ct];
        }
    }
    __syncthreads();
    if (t < 128) {
        float s  = psum[0][t] + psum[1][t];
        float mx = fmaxf(pmx[0][t], pmx[1][t]);
        pmean[((size_t)i * 4 + lt) * EE + e0 + t] = s;     // raw sum over 128 l's
        pmax[((size_t)i * 4 + lt) * EE + e0 + t]  = mx;
    }
}

// ---------------------------------------------------------------------------
// K5a: split-K partial GEMM for the output head; reduces the 4 l-tile pooling
// partials inline while loading the pooled vector.
// ---------------------------------------------------------------------------
__global__ __launch_bounds__(256) void k_out_split(
    const float* __restrict__ pmean, const float* __restrict__ pmax,
    const float* __restrict__ ow, float* __restrict__ partial)
{
    __shared__ float ps[256];
    const int kc = blockIdx.x;
    const int b  = blockIdx.y;
    const int t  = threadIdx.x;
    const int j  = kc * 256 + t;
    const int jj = (j < 2048) ? j : j - 2048;
    const int ii = 4 * b + (jj >> 9);
    const int e  = jj & 511;
    float v;
    if (j < 2048) {
        const float* bp = pmean + (size_t)ii * 4 * EE + e;
        v = (bp[0] + bp[512] + bp[1024] + bp[1536]) * (1.0f / 512.0f);
    } else {
        const float* bp = pmax + (size_t)ii * 4 * EE + e;
        v = fmaxf(fmaxf(bp[0], bp[512]), fmaxf(bp[1024], bp[1536]));
    }
    ps[t] = v;
    __syncthreads();
    f32x4 acc = {0.f, 0.f, 0.f, 0.f};
    const float* wp = ow + (size_t)kc * 256 * 1024 + t * 4;
#pragma unroll 8
    for (int q = 0; q < 256; ++q) {
        f32x4 w4 = *(const f32x4*)(wp + (size_t)q * 1024);
        float p = ps[q];
        acc[0] = fmaf(p, w4[0], acc[0]);
        acc[1] = fmaf(p, w4[1], acc[1]);
        acc[2] = fmaf(p, w4[2], acc[2]);
        acc[3] = fmaf(p, w4[3], acc[3]);
    }
    *(f32x4*)(partial + ((size_t)kc * 32 + b) * 1024 + t * 4) = acc;
}

// ---------------------------------------------------------------------------
// K5b: final reduce over 16 K-chunks + bias + relu.
// ---------------------------------------------------------------------------
__global__ __launch_bounds__(256) void k_out_final(
    const float* __restrict__ partial, const float* __restrict__ ob,
    float* __restrict__ out)
{
    const int idx = blockIdx.x * 256 + threadIdx.x;
    const int b = idx >> 10, o = idx & 1023;
    float s = ob[o];
#pragma unroll
    for (int kc = 0; kc < 16; ++kc)
        s += partial[((size_t)kc * 32 + b) * 1024 + o];
    out[idx] = fmaxf(s, 0.f);
}

// ---------------------------------------------------------------------------
extern "C" void kernel_launch(void* const* d_in, const int* in_sizes, int n_in,
                              void* d_out, int out_size, void* d_ws, size_t ws_size,
                              hipStream_t stream)
{
    const float* x1     = (const float*)d_in[0];
    const float* x2     = (const float*)d_in[1];
    const int*   x1_len = (const int*)d_in[2];
    const int*   x2_len = (const int*)d_in[3];
    const float* fw     = (const float*)d_in[4];
    const float* fb     = (const float*)d_in[5];
    const float* ow     = (const float*)d_in[6];
    const float* ob     = (const float*)d_in[7];

    float* out  = (float*)d_out;                  // [32, 1024]
    float* attn = out + (size_t)BATCH * 1024;     // [128, 512, 512] f32

    // workspace layout (~341 MB)
    char* wp = (char*)d_ws;
    unsigned short* x1bf   = (unsigned short*)wp; wp += (size_t)BATCH * LL * EE * 2;
    unsigned short* x2bf   = (unsigned short*)wp; wp += (size_t)NB * LL * EE * 2;
    unsigned short* x2t    = (unsigned short*)wp; wp += (size_t)NB * LL * EE * 2;
    unsigned short* attnbf = (unsigned short*)wp; wp += (size_t)NB * LL * LL * 2;
    unsigned short* Cbuf   = (unsigned short*)wp; wp += (size_t)NB * LL * 1024 * 2;
    unsigned short* fwt    = (unsigned short*)wp; wp += (size_t)EE * 1024 * 2;
    float* pmean   = (float*)wp; wp += (size_t)NB * 4 * EE * 4;
    float* pmax    = (float*)wp; wp += (size_t)NB * 4 * EE * 4;
    float* partial = (float*)wp; wp += (size_t)16 * BATCH * 1024 * 4;

    k_cvt_x1<<<dim3(BATCH * LL * EE / 4 / 256), 256, 0, stream>>>(x1, x1bf);
    k_cvt_x2<<<dim3(8, 8, NB), 256, 0, stream>>>(x2, x2bf, x2t);
    k_cvt_fw<<<dim3(8, 16), 256, 0, stream>>>(fw, fwt);
    k_scores_mfma<<<dim3(128, 16), 256, 0, stream>>>(x1bf, x2bf, x1_len, x2_len, attn);
    k_softmax<<<dim3(NB * LL / 4), 256, 0, stream>>>(attn, attnbf);
    k_pv_mfma<<<dim3(128, 16), 256, 0, stream>>>(attnbf, x2t, x1bf, Cbuf);
    k_fuse_mfma<<<dim3(128, 16), 256, 0, stream>>>(Cbuf, fwt, fb, pmean, pmax);
    k_out_split<<<dim3(16, BATCH), 256, 0, stream>>>(pmean, pmax, ow, partial);
    k_out_final<<<dim3(BATCH * 1024 / 256), 256, 0, stream>>>(partial, ob, out);
}